// Round 1
// baseline (47878.201 us; speedup 1.0000x reference)
//
#include <hip/hip_runtime.h>
#include <math.h>

#define BLOCK   512
#define HD      64
#define VFH     128
#define WD      5
#define NPAIR   10
#define LSDIM   16
#define LSLEN   16
#define TSN     128
#define W0S     68     // padded LDS stride for W0 rows (64+4): breaks bank conflicts, keeps 16B align
#define W1S     132    // padded LDS stride for W1 rows (128+4)
#define OUTD    (WD*HD)   // 320

// Transpose vf_w2 [320][128] -> [128][320] in workspace so per-j streaming reads
// are lane-coalesced (lane o reads w2t[j*320+o]).
__global__ void prep_w2t(const float* __restrict__ w2, float* __restrict__ w2t) {
    int g = blockIdx.x * blockDim.x + threadIdx.x;
    if (g < OUTD * VFH) {
        int r = g >> 7;          // row in [0,320)
        int j = g & (VFH - 1);   // col in [0,128)
        w2t[j * OUTD + r] = w2[g];
    }
}

template<int TR>
__global__ __launch_bounds__(BLOCK, 1)
void lncde_kernel(const float* __restrict__ ts, const float* __restrict__ logsig,
                  const float* __restrict__ x0,
                  const float* __restrict__ l1w, const float* __restrict__ l1b,
                  const float* __restrict__ l2w, const float* __restrict__ l2b,
                  const float* __restrict__ w0g, const float* __restrict__ b0g,
                  const float* __restrict__ w1g, const float* __restrict__ b1g,
                  const float* __restrict__ w2p, const float* __restrict__ b2g,
                  const int* __restrict__ pairs, const int* __restrict__ nsp,
                  float* __restrict__ outp, int dataDim)
{
    __shared__ float sW0[VFH * W0S];       // 34 KB
    __shared__ float sW1[VFH * W1S];       // 66 KB
    __shared__ float sB0[VFH], sB1[VFH], sB2[OUTD];
    __shared__ float sTs[TSN];
    __shared__ float sLs[LSLEN * LSDIM];
    __shared__ float sY[HD], sY2[HD], sK1[HD];
    __shared__ float sH0[VFH], sD0[VFH], sH1[VFH], sD1[VFH];
    __shared__ float sOut[OUTD], sDOut[OUTD];
    __shared__ float sDh0[WD * VFH], sDh1[WD * VFH];
    __shared__ float sPart[OUTD];
    __shared__ int   sPa[NPAIR], sPb[NPAIR];

    const int tid = threadIdx.x;
    const int b   = blockIdx.x;

    // ---- stage LDS: weights + tables ----
    for (int i = tid; i < VFH * HD;  i += BLOCK) sW0[(i >> 6) * W0S + (i & 63)]  = w0g[i];
    for (int i = tid; i < VFH * VFH; i += BLOCK) sW1[(i >> 7) * W1S + (i & 127)] = w1g[i];
    for (int i = tid; i < VFH; i += BLOCK) { sB0[i] = b0g[i]; sB1[i] = b1g[i]; }
    for (int i = tid; i < OUTD; i += BLOCK)          sB2[i] = b2g[i];
    for (int i = tid; i < TSN; i += BLOCK)           sTs[i] = ts[i];
    for (int i = tid; i < LSLEN * LSDIM; i += BLOCK) sLs[i] = logsig[b * LSLEN * LSDIM + i];
    if (tid < NPAIR) { sPa[tid] = pairs[2 * tid] - 1; sPb[tid] = pairs[2 * tid + 1] - 1; }
    __syncthreads();

    // y0 = x0[b,1:] @ l1w^T + l1b
    if (tid < HD) {
        float acc = l1b[tid];
        #pragma unroll
        for (int w = 0; w < WD; ++w) acc += x0[b * dataDim + 1 + w] * l1w[tid * WD + w];
        sY[tid] = acc;
    }

    // per-thread pair tables for stage G (w index = tid>>6, valid for tid<320)
    const int gw = tid >> 6;
    int pp[4] = {0,0,0,0}; int qq[4] = {0,0,0,0}; float ssg[4] = {0.f,0.f,0.f,0.f};
    {
        int n = 0;
        for (int p = 0; p < NPAIR; ++p) {
            int a = sPa[p], bb = sPb[p];
            if (a == gw && n < 4)       { qq[n] = bb; pp[n] = p; ssg[n] =  1.f; ++n; }
            else if (bb == gw && n < 4) { qq[n] = a;  pp[n] = p; ssg[n] = -1.f; ++n; }
        }
    }
    const int   q0 = qq[0], q1 = qq[1], q2 = qq[2], q3 = qq[3];
    const int   p0 = pp[0], p1 = pp[1], p2 = pp[2], p3 = pp[3];
    const float g0 = ssg[0], g1 = ssg[1], g2 = ssg[2], g3 = ssg[3];
    __syncthreads();

    const float t0v    = sTs[0];
    const int   nsteps = nsp[0];
    const float dtv    = (sTs[TSN - 1] - t0v) / (float)nsteps;
    const int   row  = tid >> 2;   // [0,128)
    const int   part = tid & 3;    // j-quarter within row

    // field(t, yv) -> mode 0: write sK1 and sY2 = y + dt*k1 ; mode 1: sY += 0.5*dt*(k1+k2)
    auto field = [&](float t, const float* __restrict__ yv, int mode) {
        // idx = min(searchsorted(ts, t, 'left') // 8, 15)   (branchless lower_bound)
        int cnt = 0;
        #pragma unroll
        for (int s = 64; s > 0; s >>= 1) {
            int c2 = cnt + s;
            if (c2 <= TSN && sTs[c2 - 1] < t) cnt = c2;
        }
        int il = cnt >> 3; il = il > (LSLEN - 1) ? (LSLEN - 1) : il;
        const float* ls = &sLs[il * LSDIM];

        // ---- B: layer0 forward: a0 = W0 @ y ----
        {
            const float4* wr = (const float4*)&sW0[row * W0S + part * 16];
            const float4* yp = (const float4*)&yv[part * 16];
            float acc = 0.f;
            #pragma unroll
            for (int k = 0; k < 4; ++k) {
                float4 w4 = wr[k], y4 = yp[k];
                acc += w4.x * y4.x + w4.y * y4.y + w4.z * y4.z + w4.w * y4.w;
            }
            acc += __shfl_xor(acc, 1, 64);
            acc += __shfl_xor(acc, 2, 64);
            if (part == 0) { float h = tanhf(acc + sB0[row]); sH0[row] = h; sD0[row] = 1.f - h * h; }
        }
        __syncthreads();
        // ---- C: layer1 forward ----
        {
            const float4* wr = (const float4*)&sW1[row * W1S + part * 32];
            const float4* hp = (const float4*)&sH0[part * 32];
            float acc = 0.f;
            #pragma unroll
            for (int k = 0; k < 8; ++k) {
                float4 w4 = wr[k], h4 = hp[k];
                acc += w4.x * h4.x + w4.y * h4.y + w4.z * h4.z + w4.w * h4.w;
            }
            acc += __shfl_xor(acc, 1, 64);
            acc += __shfl_xor(acc, 2, 64);
            if (part == 0) { float h = tanhf(acc + sB1[row]); sH1[row] = h; sD1[row] = 1.f - h * h; }
        }
        __syncthreads();
        // ---- D: layer2 forward (stream W2 from L2), rows 320 ----
        if (tid < OUTD) {
            const float* wp = TR ? (w2p + tid) : (w2p + tid * VFH);
            float acc = 0.f;
            #pragma unroll 4
            for (int j = 0; j < VFH; j += 4) {
                float4 h4 = *(const float4*)&sH1[j];
                float w0v, w1v, w2v, w3v;
                if (TR) { w0v = wp[(j+0)*OUTD]; w1v = wp[(j+1)*OUTD]; w2v = wp[(j+2)*OUTD]; w3v = wp[(j+3)*OUTD]; }
                else    { float4 wv = *(const float4*)(wp + j); w0v = wv.x; w1v = wv.y; w2v = wv.z; w3v = wv.w; }
                acc += w0v * h4.x + w1v * h4.y + w2v * h4.z + w3v * h4.w;
            }
            float h = tanhf(acc + sB2[tid]);
            sOut[tid] = h; sDOut[tid] = 1.f - h * h;
        }
        __syncthreads();
        // ---- E: tangent layer0 for all 5 tangents (tx = vf_out rows) ----
        {
            float wv[16];
            const float4* wr = (const float4*)&sW0[row * W0S + part * 16];
            #pragma unroll
            for (int k = 0; k < 4; ++k) { float4 w4 = wr[k]; wv[4*k]=w4.x; wv[4*k+1]=w4.y; wv[4*k+2]=w4.z; wv[4*k+3]=w4.w; }
            #pragma unroll
            for (int q = 0; q < WD; ++q) {
                const float4* tx = (const float4*)&sOut[q * HD + part * 16];
                float acc = 0.f;
                #pragma unroll
                for (int k = 0; k < 4; ++k) {
                    float4 t4 = tx[k];
                    acc += wv[4*k]*t4.x + wv[4*k+1]*t4.y + wv[4*k+2]*t4.z + wv[4*k+3]*t4.w;
                }
                acc += __shfl_xor(acc, 1, 64);
                acc += __shfl_xor(acc, 2, 64);
                if (part == 0) sDh0[q * VFH + row] = sD0[row] * acc;
            }
        }
        __syncthreads();
        // ---- F: tangent layer1 ----
        {
            float wv[32];
            const float4* wr = (const float4*)&sW1[row * W1S + part * 32];
            #pragma unroll
            for (int k = 0; k < 8; ++k) { float4 w4 = wr[k]; wv[4*k]=w4.x; wv[4*k+1]=w4.y; wv[4*k+2]=w4.z; wv[4*k+3]=w4.w; }
            #pragma unroll
            for (int q = 0; q < WD; ++q) {
                const float4* dp = (const float4*)&sDh0[q * VFH + part * 32];
                float acc = 0.f;
                #pragma unroll
                for (int k = 0; k < 8; ++k) {
                    float4 d4 = dp[k];
                    acc += wv[4*k]*d4.x + wv[4*k+1]*d4.y + wv[4*k+2]*d4.z + wv[4*k+3]*d4.w;
                }
                acc += __shfl_xor(acc, 1, 64);
                acc += __shfl_xor(acc, 2, 64);
                if (part == 0) sDh1[q * VFH + row] = sD1[row] * acc;
            }
        }
        __syncthreads();
        // ---- G: tangent layer2, only the 20 needed (q,w) combos + Lie combine ----
        if (tid < OUTD) {
            const float* wp = TR ? (w2p + tid) : (w2p + tid * VFH);
            float a0 = 0.f, a1 = 0.f, a2 = 0.f, a3 = 0.f;
            #pragma unroll 2
            for (int j = 0; j < VFH; j += 4) {
                float w0v, w1v, w2v, w3v;
                if (TR) { w0v = wp[(j+0)*OUTD]; w1v = wp[(j+1)*OUTD]; w2v = wp[(j+2)*OUTD]; w3v = wp[(j+3)*OUTD]; }
                else    { float4 wv4 = *(const float4*)(wp + j); w0v = wv4.x; w1v = wv4.y; w2v = wv4.z; w3v = wv4.w; }
                float4 dv0 = *(const float4*)&sDh1[q0 * VFH + j];
                float4 dv1 = *(const float4*)&sDh1[q1 * VFH + j];
                float4 dv2 = *(const float4*)&sDh1[q2 * VFH + j];
                float4 dv3 = *(const float4*)&sDh1[q3 * VFH + j];
                a0 += w0v*dv0.x + w1v*dv0.y + w2v*dv0.z + w3v*dv0.w;
                a1 += w0v*dv1.x + w1v*dv1.y + w2v*dv1.z + w3v*dv1.w;
                a2 += w0v*dv2.x + w1v*dv2.y + w2v*dv2.z + w3v*dv2.w;
                a3 += w0v*dv3.x + w1v*dv3.y + w2v*dv3.z + w3v*dv3.w;
            }
            float der = sDOut[tid];
            sPart[tid] = ls[1 + gw] * sOut[tid]
                + der * ( g0 * ls[6 + p0] * a0 + g1 * ls[6 + p1] * a1
                        + g2 * ls[6 + p2] * a2 + g3 * ls[6 + p3] * a3 );
        }
        __syncthreads();
        // ---- H: reduce over w, Heun glue ----
        if (tid < HD) {
            float k = sPart[tid] + sPart[HD + tid] + sPart[2*HD + tid]
                    + sPart[3*HD + tid] + sPart[4*HD + tid];
            if (mode == 0) { sK1[tid] = k; sY2[tid] = sY[tid] + dtv * k; }
            else           { sY[tid] = sY[tid] + 0.5f * dtv * (sK1[tid] + k); }
        }
        __syncthreads();
    };

    for (int i = 0; i < nsteps; ++i) {
        float t = t0v + (float)i * dtv;
        field(t, sY, 0);
        field(t + dtv, sY2, 1);
    }

    // epilogue: logits = yT @ l2w^T + l2b ; softmax
    if (tid == 0) {
        float lg[10];
        float mx = -3.4e38f;
        for (int l = 0; l < 10; ++l) {
            float acc = l2b[l];
            for (int h = 0; h < HD; ++h) acc += sY[h] * l2w[l * HD + h];
            lg[l] = acc; mx = fmaxf(mx, acc);
        }
        float sum = 0.f;
        for (int l = 0; l < 10; ++l) { lg[l] = expf(lg[l] - mx); sum += lg[l]; }
        float inv = 1.f / sum;
        for (int l = 0; l < 10; ++l) outp[b * 10 + l] = lg[l] * inv;
    }
}

extern "C" void kernel_launch(void* const* d_in, const int* in_sizes, int n_in,
                              void* d_out, int out_size, void* d_ws, size_t ws_size,
                              hipStream_t stream) {
    const float* ts     = (const float*)d_in[0];
    const float* logsig = (const float*)d_in[1];
    const float* x0     = (const float*)d_in[2];
    const float* l1w    = (const float*)d_in[3];
    const float* l1b    = (const float*)d_in[4];
    const float* l2w    = (const float*)d_in[5];
    const float* l2b    = (const float*)d_in[6];
    const float* w0     = (const float*)d_in[7];
    const float* b0     = (const float*)d_in[8];
    const float* w1     = (const float*)d_in[9];
    const float* b1     = (const float*)d_in[10];
    const float* w2     = (const float*)d_in[11];
    const float* b2     = (const float*)d_in[12];
    const int*   pairs  = (const int*)d_in[13];
    const int*   nsp    = (const int*)d_in[14];
    float* outp = (float*)d_out;

    const int B = in_sizes[1] / (LSLEN * LSDIM);           // batches from logsig size
    const int dataDim = in_sizes[2] / (B > 0 ? B : 1);     // 6

    const bool tr = ws_size >= (size_t)(OUTD * VFH * sizeof(float));
    float* w2t = (float*)d_ws;

    if (tr) {
        hipLaunchKernelGGL(prep_w2t, dim3((OUTD * VFH + 255) / 256), dim3(256), 0, stream, w2, w2t);
        hipLaunchKernelGGL((lncde_kernel<1>), dim3(B), dim3(BLOCK), 0, stream,
                           ts, logsig, x0, l1w, l1b, l2w, l2b,
                           w0, b0, w1, b1, (const float*)w2t, b2, pairs, nsp, outp, dataDim);
    } else {
        hipLaunchKernelGGL((lncde_kernel<0>), dim3(B), dim3(BLOCK), 0, stream,
                           ts, logsig, x0, l1w, l1b, l2w, l2b,
                           w0, b0, w1, b1, w2, b2, pairs, nsp, outp, dataDim);
    }
}